// Round 1
// baseline (1273.290 us; speedup 1.0000x reference)
//
#include <hip/hip_runtime.h>

// VM-factorized voxel grid eval: N points -> 48 features (3 planes x 16ch) -> 27 outputs.
// G=1, N=2097152, C=16, R=320, NCOMP=48, F=27. All fp32.

constexpr int NPTS = 2097152;
constexpr int CCH  = 16;      // channels per plane
constexpr int RES  = 320;
constexpr long long HW = (long long)RES * RES;
constexpr int FD   = 27;      // output features
constexpr int BLK  = 256;

__device__ __forceinline__ float bilerp(const float* __restrict__ p,
                                        int o00, int o01, int o10, int o11,
                                        float wc, float wr) {
    float v00 = p[o00], v01 = p[o01], v10 = p[o10], v11 = p[o11];
    float top = v00 + wc * (v01 - v00);
    float bot = v10 + wc * (v11 - v10);
    return top + wr * (bot - top);
}

__global__ __launch_bounds__(BLK) void vm_eval(
    const float* __restrict__ pts,
    const float* __restrict__ pxy,   // (16,320,320)  u=px->W, v=py->H
    const float* __restrict__ pyz,   // (16,320,320)  u=py->W, v=pz->H
    const float* __restrict__ pxz,   // (16,320,320)  u=px->W, v=pz->H
    const float* __restrict__ vx,    // (16,320)  t=px
    const float* __restrict__ vy,    // (16,320)  t=py
    const float* __restrict__ vz,    // (16,320)  t=pz
    const float* __restrict__ basis, // (48,27)
    float* __restrict__ out)         // (N,27)
{
    __shared__ float s_out[BLK * FD];   // 27648 B
    const int tid = threadIdx.x;
    const long long i = (long long)blockIdx.x * BLK + tid;

    const float px = pts[i * 3 + 0];
    const float py = pts[i * 3 + 1];
    const float pz = pts[i * 3 + 2];

    const float sc = 0.5f * (RES - 1);
    const float fx = (px + 1.f) * sc;
    const float fy = (py + 1.f) * sc;
    const float fz = (pz + 1.f) * sc;
    const float xf = floorf(fx), yf = floorf(fy), zf = floorf(fz);
    const float wx = fx - xf, wy = fy - yf, wz = fz - zf;
    int x0 = (int)xf, y0 = (int)yf, z0 = (int)zf;
    // inputs are in [-1,1) so indices are in range; clamp for safety.
    // upper-corner clamp is exact: when x0==RES-1, wx==0 so the clamped corner has weight 0.
    x0 = min(max(x0, 0), RES - 1);
    y0 = min(max(y0, 0), RES - 1);
    z0 = min(max(z0, 0), RES - 1);
    const int x1 = min(x0 + 1, RES - 1);
    const int y1 = min(y0 + 1, RES - 1);
    const int z1 = min(z0 + 1, RES - 1);

    // per-channel corner offsets (row-major [row][col], row stride RES)
    const int xy00 = y0 * RES + x0, xy01 = y0 * RES + x1, xy10 = y1 * RES + x0, xy11 = y1 * RES + x1;
    const int xz00 = z0 * RES + x0, xz01 = z0 * RES + x1, xz10 = z1 * RES + x0, xz11 = z1 * RES + x1;
    const int yz00 = z0 * RES + y0, yz01 = z0 * RES + y1, yz10 = z1 * RES + y0, yz11 = z1 * RES + y1;

    float acc[FD];
    #pragma unroll
    for (int f = 0; f < FD; ++f) acc[f] = 0.f;

    #pragma unroll 4
    for (int c = 0; c < CCH; ++c) {
        const float* a = pxy + c * HW;
        const float* b = pxz + c * HW;
        const float* d = pyz + c * HW;
        float lz = vz[c * RES + z0]; lz += wz * (vz[c * RES + z1] - lz);
        float ly = vy[c * RES + y0]; ly += wy * (vy[c * RES + y1] - ly);
        float lx = vx[c * RES + x0]; lx += wx * (vx[c * RES + x1] - lx);
        const float fa = bilerp(a, xy00, xy01, xy10, xy11, wx, wy) * lz; // xy plane * z line
        const float fb = bilerp(b, xz00, xz01, xz10, xz11, wx, wz) * ly; // xz plane * y line
        const float fc = bilerp(d, yz00, yz01, yz10, yz11, wy, wz) * lx; // yz plane * x line
        // basis rows: [0..15]=a, [16..31]=b, [32..47]=c. Uniform addresses -> s_load + SGPR-FMA.
        #pragma unroll
        for (int f = 0; f < FD; ++f) {
            float s = acc[f];
            s += fa * basis[(c          ) * FD + f];
            s += fb * basis[(CCH + c    ) * FD + f];
            s += fc * basis[(2 * CCH + c) * FD + f];
            acc[f] = s;
        }
    }

    // stage to LDS (stride 27 = odd -> conflict-free), then coalesced float4 store
    #pragma unroll
    for (int f = 0; f < FD; ++f) s_out[tid * FD + f] = acc[f];
    __syncthreads();

    float4* ob = (float4*)(out + (size_t)blockIdx.x * BLK * FD);
    const float4* s4 = (const float4*)s_out;
    #pragma unroll
    for (int k = 0; k < 7; ++k) {
        int idx = tid + k * BLK;
        if (idx < BLK * FD / 4) ob[idx] = s4[idx];
    }
}

extern "C" void kernel_launch(void* const* d_in, const int* in_sizes, int n_in,
                              void* d_out, int out_size, void* d_ws, size_t ws_size,
                              hipStream_t stream) {
    const float* pts   = (const float*)d_in[0];
    const float* pxy   = (const float*)d_in[1];
    const float* pyz   = (const float*)d_in[2];
    const float* pxz   = (const float*)d_in[3];
    const float* vx    = (const float*)d_in[4];
    const float* vy    = (const float*)d_in[5];
    const float* vz    = (const float*)d_in[6];
    const float* basis = (const float*)d_in[7];
    float* out = (float*)d_out;

    dim3 grid(NPTS / BLK);
    vm_eval<<<grid, BLK, 0, stream>>>(pts, pxy, pyz, pxz, vx, vy, vz, basis, out);
}

// Round 2
// 520.927 us; speedup vs baseline: 2.4443x; 2.4443x over previous
//
#include <hip/hip_runtime.h>
#include <stdint.h>

// VM-factorized voxel grid: N pts -> 48 feats (3 planes x 16ch) -> 27 outputs.
// G=1, N=2097152, C=16, R=320, NCOMP=48, F=27, fp32.
//
// Strategy: (1) transform planes to channel-last (texel-major, 16ch = one 64B line),
// (2) counting-sort points by Morton 32^3 cell for gather locality,
// (3) eval kernel reads sorted payload coalesced, gathers L2-resident plane lines,
//     scatter-writes 27 floats to original point slot.

constexpr int NPTS = 2097152;
constexpr int CCH  = 16;
constexpr int RES  = 320;
constexpr long long HW = (long long)RES * RES;   // 102400
constexpr int FD   = 27;
constexpr int BLK  = 256;
constexpr int NCELL = 32768;                     // 32^3 cells of ~10 texels/axis

// ---- workspace layout (bytes) ----
constexpr size_t WS_PLANEST = 0;                                  // 3*HW*16*4 = 19,660,800
constexpr size_t WS_LINEST  = WS_PLANEST + 3ull*HW*CCH*4;         // 3*320*16*4 = 61,440
constexpr size_t WS_HIST    = WS_LINEST + 3ull*RES*CCH*4;         // 131,072
constexpr size_t WS_CURSOR  = WS_HIST + (size_t)NCELL*4;          // 131,072
constexpr size_t WS_SORTED  = WS_CURSOR + (size_t)NCELL*4;        // N*16 = 33,554,432
constexpr size_t WS_NEED    = WS_SORTED + (size_t)NPTS*16;        // ~53.6 MB

// ---------------- helpers ----------------
__device__ __forceinline__ unsigned spread5(unsigned v) {
    // 5 bits -> bits {0,3,6,9,12}
    return (v & 1u) | ((v & 2u) << 2) | ((v & 4u) << 4) | ((v & 8u) << 6) | ((v & 16u) << 8);
}

__device__ __forceinline__ int cell_key(float px, float py, float pz) {
    int cx = min(max((int)((px + 1.f) * 16.f), 0), 31);
    int cy = min(max((int)((py + 1.f) * 16.f), 0), 31);
    int cz = min(max((int)((pz + 1.f) * 16.f), 0), 31);
    return (int)(spread5((unsigned)cx) | (spread5((unsigned)cy) << 1) | (spread5((unsigned)cz) << 2));
}

__device__ __forceinline__ float4 fma4(float w, float4 a, float4 s) {
    s.x = fmaf(w, a.x, s.x); s.y = fmaf(w, a.y, s.y);
    s.z = fmaf(w, a.z, s.z); s.w = fmaf(w, a.w, s.w);
    return s;
}

// ---------------- pipeline kernels ----------------
__global__ void zero_hist(unsigned* __restrict__ h) {
    h[blockIdx.x * BLK + threadIdx.x] = 0u;
}

// planes (C,H,W) -> (H*W, C); blockIdx.y selects plane {0:xy, 1:xz, 2:yz}
__global__ void transform_planes(const float* __restrict__ s0, const float* __restrict__ s1,
                                 const float* __restrict__ s2, float* __restrict__ dst) {
    const float* src = (blockIdx.y == 0) ? s0 : (blockIdx.y == 1 ? s1 : s2);
    float* d = dst + (size_t)blockIdx.y * HW * CCH;
    const int texel = blockIdx.x * BLK + threadIdx.x;   // gridDim.x = 400 -> exact
    float v[CCH];
    #pragma unroll
    for (int c = 0; c < CCH; ++c) v[c] = src[(size_t)c * HW + texel];
    float4* d4 = (float4*)(d + (size_t)texel * CCH);
    #pragma unroll
    for (int q = 0; q < 4; ++q) d4[q] = make_float4(v[q*4], v[q*4+1], v[q*4+2], v[q*4+3]);
}

// lines (C,L) -> (L,C); axes 0:x 1:y 2:z
__global__ void transform_lines(const float* __restrict__ vx, const float* __restrict__ vy,
                                const float* __restrict__ vz, float* __restrict__ dst) {
    const float* src = (blockIdx.y == 0) ? vx : (blockIdx.y == 1 ? vy : vz);
    float* d = dst + (size_t)blockIdx.y * RES * CCH;
    const int t = blockIdx.x * BLK + threadIdx.x;       // gridDim.x = 2 -> 512 threads, guard
    if (t >= RES) return;
    float v[CCH];
    #pragma unroll
    for (int c = 0; c < CCH; ++c) v[c] = src[c * RES + t];
    float4* d4 = (float4*)(d + (size_t)t * CCH);
    #pragma unroll
    for (int q = 0; q < 4; ++q) d4[q] = make_float4(v[q*4], v[q*4+1], v[q*4+2], v[q*4+3]);
}

__global__ void hist_kernel(const float* __restrict__ pts, unsigned* __restrict__ hist) {
    const int i = blockIdx.x * BLK + threadIdx.x;
    const float px = pts[3*i], py = pts[3*i+1], pz = pts[3*i+2];
    atomicAdd(&hist[cell_key(px, py, pz)], 1u);
}

__global__ __launch_bounds__(1024) void scan_kernel(const unsigned* __restrict__ hist,
                                                    unsigned* __restrict__ cursor) {
    __shared__ unsigned lsum[1024];
    const int t = threadIdx.x;
    const int base = t * 32;
    unsigned local[32];
    unsigned run = 0;
    #pragma unroll
    for (int k = 0; k < 32; ++k) { unsigned v = hist[base + k]; local[k] = run; run += v; }
    lsum[t] = run;
    __syncthreads();
    for (int o = 1; o < 1024; o <<= 1) {
        unsigned v = (t >= o) ? lsum[t - o] : 0u;
        __syncthreads();
        lsum[t] += v;
        __syncthreads();
    }
    const unsigned b = lsum[t] - run;   // exclusive base for this thread's chunk
    #pragma unroll
    for (int k = 0; k < 32; ++k) cursor[base + k] = b + local[k];
}

__global__ void scatter_kernel(const float* __restrict__ pts, unsigned* __restrict__ cursor,
                               float4* __restrict__ sorted) {
    const int i = blockIdx.x * BLK + threadIdx.x;
    const float px = pts[3*i], py = pts[3*i+1], pz = pts[3*i+2];
    const unsigned pos = atomicAdd(&cursor[cell_key(px, py, pz)], 1u);
    sorted[pos] = make_float4(px, py, pz, __int_as_float(i));
}

// ---------------- eval ----------------
__device__ __forceinline__ void plane_acc(const float4* __restrict__ P,
                                          int t00, int t01, int t10, int t11,
                                          float wc, float wr, float4 s[4]) {
    const float w00 = (1.f - wc) * (1.f - wr), w01 = wc * (1.f - wr);
    const float w10 = (1.f - wc) * wr,         w11 = wc * wr;
    const float4* p00 = P + (size_t)t00 * 4;
    const float4* p01 = P + (size_t)t01 * 4;
    const float4* p10 = P + (size_t)t10 * 4;
    const float4* p11 = P + (size_t)t11 * 4;
    #pragma unroll
    for (int q = 0; q < 4; ++q) {
        float4 v = make_float4(w00*p00[q].x, w00*p00[q].y, w00*p00[q].z, w00*p00[q].w);
        v = fma4(w01, p01[q], v);
        v = fma4(w10, p10[q], v);
        v = fma4(w11, p11[q], v);
        s[q] = v;
    }
}

__device__ __forceinline__ void line_mul(const float4* __restrict__ L, int t0, int t1,
                                         float w, float4 s[4]) {
    const float4* a = L + (size_t)t0 * 4;
    const float4* b = L + (size_t)t1 * 4;
    #pragma unroll
    for (int q = 0; q < 4; ++q) {
        float4 av = a[q], bv = b[q];
        s[q].x *= fmaf(w, bv.x - av.x, av.x);
        s[q].y *= fmaf(w, bv.y - av.y, av.y);
        s[q].z *= fmaf(w, bv.z - av.z, av.z);
        s[q].w *= fmaf(w, bv.w - av.w, av.w);
    }
}

__global__ __launch_bounds__(BLK) void eval_kernel(
    const float4* __restrict__ sorted,
    const float* __restrict__ planesT,
    const float* __restrict__ linesT,
    const float* __restrict__ basis,
    float* __restrict__ out) {
    constexpr int NBLK = NPTS / BLK;            // 8192
    constexpr int CHUNK = NBLK / 8;             // 1024
    const int bid = blockIdx.x;
    const int swz = (bid & 7) * CHUNK + (bid >> 3);   // each XCD gets a contiguous sorted range
    const int j = swz * BLK + threadIdx.x;

    const float4 pt = sorted[j];
    const float px = pt.x, py = pt.y, pz = pt.z;
    const long long oi = (long long)__float_as_int(pt.w);

    const float scl = 0.5f * (RES - 1);
    const float fx = (px + 1.f) * scl, fy = (py + 1.f) * scl, fz = (pz + 1.f) * scl;
    const float xf = floorf(fx), yf = floorf(fy), zf = floorf(fz);
    const float wx = fx - xf, wy = fy - yf, wz = fz - zf;
    int x0 = min(max((int)xf, 0), RES - 1);
    int y0 = min(max((int)yf, 0), RES - 1);
    int z0 = min(max((int)zf, 0), RES - 1);
    const int x1 = min(x0 + 1, RES - 1);
    const int y1 = min(y0 + 1, RES - 1);
    const int z1 = min(z0 + 1, RES - 1);

    const float4* Pxy = (const float4*)planesT;
    const float4* Pxz = (const float4*)(planesT + (size_t)HW * CCH);
    const float4* Pyz = (const float4*)(planesT + (size_t)2 * HW * CCH);
    const float4* Lx = (const float4*)linesT;
    const float4* Ly = (const float4*)(linesT + (size_t)RES * CCH);
    const float4* Lz = (const float4*)(linesT + (size_t)2 * RES * CCH);

    float4 sa[4], sb[4], sc4[4];
    plane_acc(Pxy, y0*RES + x0, y0*RES + x1, y1*RES + x0, y1*RES + x1, wx, wy, sa);
    plane_acc(Pxz, z0*RES + x0, z0*RES + x1, z1*RES + x0, z1*RES + x1, wx, wz, sb);
    plane_acc(Pyz, z0*RES + y0, z0*RES + y1, z1*RES + y0, z1*RES + y1, wy, wz, sc4);
    line_mul(Lz, z0, z1, wz, sa);   // a = xy-plane * z-line
    line_mul(Ly, y0, y1, wy, sb);   // b = xz-plane * y-line
    line_mul(Lx, x0, x1, wx, sc4);  // c = yz-plane * x-line

    float fe[48];
    #pragma unroll
    for (int q = 0; q < 4; ++q) {
        fe[     q*4+0] = sa[q].x;  fe[     q*4+1] = sa[q].y;  fe[     q*4+2] = sa[q].z;  fe[     q*4+3] = sa[q].w;
        fe[16 + q*4+0] = sb[q].x;  fe[16 + q*4+1] = sb[q].y;  fe[16 + q*4+2] = sb[q].z;  fe[16 + q*4+3] = sb[q].w;
        fe[32 + q*4+0] = sc4[q].x; fe[32 + q*4+1] = sc4[q].y; fe[32 + q*4+2] = sc4[q].z; fe[32 + q*4+3] = sc4[q].w;
    }

    float acc[FD];
    #pragma unroll
    for (int f = 0; f < FD; ++f) acc[f] = 0.f;
    #pragma unroll
    for (int r = 0; r < 48; ++r) {
        const float fv = fe[r];
        #pragma unroll
        for (int f = 0; f < FD; ++f) acc[f] = fmaf(fv, basis[r * FD + f], acc[f]);
    }

    float* op = out + oi * FD;
    #pragma unroll
    for (int f = 0; f < FD; ++f) op[f] = acc[f];
}

// ---------------- fallback (round-1 kernel, used only if ws too small) ----------------
__device__ __forceinline__ float bilerp(const float* __restrict__ p,
                                        int o00, int o01, int o10, int o11,
                                        float wc, float wr) {
    float v00 = p[o00], v01 = p[o01], v10 = p[o10], v11 = p[o11];
    float top = v00 + wc * (v01 - v00);
    float bot = v10 + wc * (v11 - v10);
    return top + wr * (bot - top);
}

__global__ __launch_bounds__(BLK) void vm_eval_fallback(
    const float* __restrict__ pts,
    const float* __restrict__ pxy, const float* __restrict__ pyz, const float* __restrict__ pxz,
    const float* __restrict__ vx, const float* __restrict__ vy, const float* __restrict__ vz,
    const float* __restrict__ basis, float* __restrict__ out) {
    const int tid = threadIdx.x;
    const long long i = (long long)blockIdx.x * BLK + tid;
    const float px = pts[i*3], py = pts[i*3+1], pz = pts[i*3+2];
    const float scl = 0.5f * (RES - 1);
    const float fx = (px + 1.f) * scl, fy = (py + 1.f) * scl, fz = (pz + 1.f) * scl;
    const float xf = floorf(fx), yf = floorf(fy), zf = floorf(fz);
    const float wx = fx - xf, wy = fy - yf, wz = fz - zf;
    int x0 = min(max((int)xf, 0), RES - 1);
    int y0 = min(max((int)yf, 0), RES - 1);
    int z0 = min(max((int)zf, 0), RES - 1);
    const int x1 = min(x0+1, RES-1), y1 = min(y0+1, RES-1), z1 = min(z0+1, RES-1);
    const int xy00=y0*RES+x0, xy01=y0*RES+x1, xy10=y1*RES+x0, xy11=y1*RES+x1;
    const int xz00=z0*RES+x0, xz01=z0*RES+x1, xz10=z1*RES+x0, xz11=z1*RES+x1;
    const int yz00=z0*RES+y0, yz01=z0*RES+y1, yz10=z1*RES+y0, yz11=z1*RES+y1;
    float acc[FD];
    #pragma unroll
    for (int f = 0; f < FD; ++f) acc[f] = 0.f;
    #pragma unroll 4
    for (int c = 0; c < CCH; ++c) {
        const float* a = pxy + c * HW;
        const float* b = pxz + c * HW;
        const float* d = pyz + c * HW;
        float lz = vz[c*RES+z0]; lz += wz * (vz[c*RES+z1] - lz);
        float ly = vy[c*RES+y0]; ly += wy * (vy[c*RES+y1] - ly);
        float lx = vx[c*RES+x0]; lx += wx * (vx[c*RES+x1] - lx);
        const float fa = bilerp(a, xy00, xy01, xy10, xy11, wx, wy) * lz;
        const float fb = bilerp(b, xz00, xz01, xz10, xz11, wx, wz) * ly;
        const float fc = bilerp(d, yz00, yz01, yz10, yz11, wy, wz) * lx;
        #pragma unroll
        for (int f = 0; f < FD; ++f) {
            float s = acc[f];
            s += fa * basis[c*FD+f];
            s += fb * basis[(CCH+c)*FD+f];
            s += fc * basis[(2*CCH+c)*FD+f];
            acc[f] = s;
        }
    }
    float* op = out + i * FD;
    #pragma unroll
    for (int f = 0; f < FD; ++f) op[f] = acc[f];
}

extern "C" void kernel_launch(void* const* d_in, const int* in_sizes, int n_in,
                              void* d_out, int out_size, void* d_ws, size_t ws_size,
                              hipStream_t stream) {
    const float* pts   = (const float*)d_in[0];
    const float* pxy   = (const float*)d_in[1];
    const float* pyz   = (const float*)d_in[2];
    const float* pxz   = (const float*)d_in[3];
    const float* vx    = (const float*)d_in[4];
    const float* vy    = (const float*)d_in[5];
    const float* vz    = (const float*)d_in[6];
    const float* basis = (const float*)d_in[7];
    float* out = (float*)d_out;

    if (ws_size < WS_NEED) {
        vm_eval_fallback<<<NPTS / BLK, BLK, 0, stream>>>(pts, pxy, pyz, pxz, vx, vy, vz, basis, out);
        return;
    }

    uint8_t* w = (uint8_t*)d_ws;
    float*    planesT = (float*)(w + WS_PLANEST);
    float*    linesT  = (float*)(w + WS_LINEST);
    unsigned* hist    = (unsigned*)(w + WS_HIST);
    unsigned* cursor  = (unsigned*)(w + WS_CURSOR);
    float4*   sorted  = (float4*)(w + WS_SORTED);

    zero_hist<<<NCELL / BLK, BLK, 0, stream>>>(hist);
    transform_planes<<<dim3(RES * RES / BLK, 3), BLK, 0, stream>>>(pxy, pxz, pyz, planesT);
    transform_lines<<<dim3(2, 3), BLK, 0, stream>>>(vx, vy, vz, linesT);
    hist_kernel<<<NPTS / BLK, BLK, 0, stream>>>(pts, hist);
    scan_kernel<<<1, 1024, 0, stream>>>(hist, cursor);
    scatter_kernel<<<NPTS / BLK, BLK, 0, stream>>>(pts, cursor, sorted);
    eval_kernel<<<NPTS / BLK, BLK, 0, stream>>>(sorted, planesT, linesT, basis, out);
}

// Round 3
// 459.344 us; speedup vs baseline: 2.7720x; 1.1341x over previous
//
#include <hip/hip_runtime.h>
#include <hip/hip_fp16.h>
#include <stdint.h>

// VM-factorized voxel grid: N pts -> 48 feats (3 planes x 16ch) -> 27 outputs.
// Pipeline: memset hist -> fused transform (planes/lines -> fp16 channel-last,
// basis -> padded float2[48][14]) -> Morton-cell counting sort -> eval
// (fp16 gathers, v_pk_fma_f32 matmul, scattered 27-dword store).

constexpr int NPTS = 2097152;
constexpr int CCH  = 16;
constexpr int RES  = 320;
constexpr long long HW = (long long)RES * RES;   // 102400
constexpr int FD   = 27;
constexpr int BLK  = 256;
constexpr int NCELL = 32768;                     // 32^3 Morton cells

// ---- workspace layout (bytes), all 16B-aligned ----
constexpr size_t WS_PLANEH = 0;                                   // 3*HW*16*2 = 9,830,400
constexpr size_t WS_LINEH  = WS_PLANEH + 3ull*HW*CCH*2;           // 3*320*16*2 = 30,720
constexpr size_t WS_BPAD   = WS_LINEH + 3ull*RES*CCH*2;           // 48*14*8 = 5,376
constexpr size_t WS_HIST   = WS_BPAD + 48ull*14*8;                // 131,072
constexpr size_t WS_CURSOR = WS_HIST + (size_t)NCELL*4;           // 131,072
constexpr size_t WS_SORTED = WS_CURSOR + (size_t)NCELL*4;         // N*16
constexpr size_t WS_NEED   = WS_SORTED + (size_t)NPTS*16;         // ~43.7 MB

// ---------------- helpers ----------------
__device__ __forceinline__ unsigned spread5(unsigned v) {
    return (v & 1u) | ((v & 2u) << 2) | ((v & 4u) << 4) | ((v & 8u) << 6) | ((v & 16u) << 8);
}
__device__ __forceinline__ int cell_key(float px, float py, float pz) {
    int cx = min(max((int)((px + 1.f) * 16.f), 0), 31);
    int cy = min(max((int)((py + 1.f) * 16.f), 0), 31);
    int cz = min(max((int)((pz + 1.f) * 16.f), 0), 31);
    return (int)(spread5((unsigned)cx) | (spread5((unsigned)cy) << 1) | (spread5((unsigned)cz) << 2));
}

// packed fp32 FMA: acc = ab * b + acc ; b comes from SGPR pair (uniform basis)
__device__ __forceinline__ void pk_fma(float2& acc, const float2 ab, const float2 b) {
    unsigned long long bs;
    __builtin_memcpy(&bs, &b, 8);
    asm("v_pk_fma_f32 %0, %1, %2, %0" : "+v"(acc) : "v"(ab), "s"(bs));
}

__device__ __forceinline__ float2 h2f(unsigned u) {
    __half2 h = *(__half2*)&u;
    return __half22float2(h);
}
__device__ __forceinline__ unsigned lane_of(uint4 q, int j) {
    return j == 0 ? q.x : (j == 1 ? q.y : (j == 2 ? q.z : q.w));
}

// ---------------- transform: planes/lines -> fp16 channel-last; basis pad ----------------
__global__ __launch_bounds__(BLK) void transform_all(
    const float* __restrict__ pxy, const float* __restrict__ pxz, const float* __restrict__ pyz,
    const float* __restrict__ vx, const float* __restrict__ vy, const float* __restrict__ vz,
    const float* __restrict__ basis,
    __half* __restrict__ planesH, __half* __restrict__ linesH, float2* __restrict__ bpad) {
    const int bid = blockIdx.x;
    const int tid = threadIdx.x;
    if (bid < 1200) {                       // planes: 3 x 400 blocks
        const int plane = bid / 400;
        const int texel = (bid % 400) * BLK + tid;
        const float* src = (plane == 0) ? pxy : (plane == 1 ? pxz : pyz);
        union { ushort u[16]; uint4 q[2]; } pk;
        #pragma unroll
        for (int c = 0; c < CCH; ++c)
            pk.u[c] = __half_as_ushort(__float2half(src[(size_t)c * HW + texel]));
        uint4* dst = (uint4*)(planesH + ((size_t)plane * HW + texel) * CCH);
        dst[0] = pk.q[0]; dst[1] = pk.q[1];
    } else if (bid < 1204) {                // lines: 3 axes x 320
        const int idx = (bid - 1200) * BLK + tid;
        if (idx >= 3 * RES) return;
        const int axis = idx / RES, t = idx % RES;
        const float* src = (axis == 0) ? vx : (axis == 1 ? vy : vz);
        union { ushort u[16]; uint4 q[2]; } pk;
        #pragma unroll
        for (int c = 0; c < CCH; ++c)
            pk.u[c] = __half_as_ushort(__float2half(src[c * RES + t]));
        uint4* dst = (uint4*)(linesH + ((size_t)axis * RES + t) * CCH);
        dst[0] = pk.q[0]; dst[1] = pk.q[1];
    } else {                                // basis (48,27) -> padded float2 (48,14)
        for (int k = tid; k < 48 * 14; k += BLK) {
            const int r = k / 14, f = k % 14;
            float x = basis[r * FD + 2 * f];
            float y = (2 * f + 1 < FD) ? basis[r * FD + 2 * f + 1] : 0.f;
            bpad[k] = make_float2(x, y);
        }
    }
}

// ---------------- sort pipeline ----------------
__global__ __launch_bounds__(BLK) void hist_kernel(const float* __restrict__ pts,
                                                   unsigned* __restrict__ hist) {
    const int i = blockIdx.x * BLK + threadIdx.x;
    atomicAdd(&hist[cell_key(pts[3*i], pts[3*i+1], pts[3*i+2])], 1u);
}

__global__ __launch_bounds__(1024) void scan_kernel(const unsigned* __restrict__ hist,
                                                    unsigned* __restrict__ cursor) {
    __shared__ unsigned lsum[1024];
    const int t = threadIdx.x;
    const int base = t * 32;
    const uint4* h4 = (const uint4*)(hist + base);
    unsigned local[32];
    unsigned run = 0;
    #pragma unroll
    for (int q = 0; q < 8; ++q) {
        uint4 v = h4[q];
        local[4*q+0] = run; run += v.x;
        local[4*q+1] = run; run += v.y;
        local[4*q+2] = run; run += v.z;
        local[4*q+3] = run; run += v.w;
    }
    lsum[t] = run;
    __syncthreads();
    for (int o = 1; o < 1024; o <<= 1) {
        unsigned v = (t >= o) ? lsum[t - o] : 0u;
        __syncthreads();
        lsum[t] += v;
        __syncthreads();
    }
    const unsigned b = lsum[t] - run;
    uint4* c4 = (uint4*)(cursor + base);
    #pragma unroll
    for (int q = 0; q < 8; ++q)
        c4[q] = make_uint4(b + local[4*q+0], b + local[4*q+1], b + local[4*q+2], b + local[4*q+3]);
}

__global__ __launch_bounds__(BLK) void scatter_kernel(const float* __restrict__ pts,
                                                      unsigned* __restrict__ cursor,
                                                      float4* __restrict__ sorted) {
    const int i = blockIdx.x * BLK + threadIdx.x;
    const float px = pts[3*i], py = pts[3*i+1], pz = pts[3*i+2];
    const unsigned pos = atomicAdd(&cursor[cell_key(px, py, pz)], 1u);
    sorted[pos] = make_float4(px, py, pz, __int_as_float(i));
}

// ---------------- eval ----------------
// One 8-channel half: 4 corner uint4 + 2 line uint4 loads, bilerp+line in f32,
// then 8 rows of packed matmul into acc.
__device__ __forceinline__ void do_half(const uint4* __restrict__ P, const uint4* __restrict__ L,
                                        int t00, int t01, int t10, int t11, int l0, int l1,
                                        float wc, float wr, float lw, int h, int rbase,
                                        const float2* __restrict__ bp, float2 acc[14]) {
    const uint4 c00 = P[2*t00 + h], c01 = P[2*t01 + h];
    const uint4 c10 = P[2*t10 + h], c11 = P[2*t11 + h];
    const uint4 la4 = L[2*l0 + h],  lb4 = L[2*l1 + h];
    const float w00 = (1.f - wc) * (1.f - wr), w01 = wc * (1.f - wr);
    const float w10 = (1.f - wc) * wr,         w11 = wc * wr;
    #pragma unroll
    for (int j = 0; j < 4; ++j) {
        const float2 v00 = h2f(lane_of(c00, j)), v01 = h2f(lane_of(c01, j));
        const float2 v10 = h2f(lane_of(c10, j)), v11 = h2f(lane_of(c11, j));
        float sx = w00 * v00.x + w01 * v01.x + w10 * v10.x + w11 * v11.x;
        float sy = w00 * v00.y + w01 * v01.y + w10 * v10.y + w11 * v11.y;
        const float2 la = h2f(lane_of(la4, j)), lb = h2f(lane_of(lb4, j));
        sx *= fmaf(lw, lb.x - la.x, la.x);
        sy *= fmaf(lw, lb.y - la.y, la.y);
        const int r0 = rbase + 8 * h + 2 * j;
        const float2 fx2 = make_float2(sx, sx);
        #pragma unroll
        for (int f = 0; f < 14; ++f) pk_fma(acc[f], fx2, bp[r0 * 14 + f]);
        const float2 fy2 = make_float2(sy, sy);
        #pragma unroll
        for (int f = 0; f < 14; ++f) pk_fma(acc[f], fy2, bp[(r0 + 1) * 14 + f]);
    }
}

__global__ __launch_bounds__(BLK, 6) void eval_kernel(
    const float4* __restrict__ sorted,
    const __half* __restrict__ planesH,
    const __half* __restrict__ linesH,
    const float2* __restrict__ bp,
    float* __restrict__ out) {
    constexpr int NBLK = NPTS / BLK;            // 8192
    constexpr int CHUNK = NBLK / 8;             // 1024
    const int bid = blockIdx.x;
    const int swz = (bid & 7) * CHUNK + (bid >> 3);   // contiguous sorted range per XCD
    const int j = swz * BLK + threadIdx.x;

    const float4 pt = sorted[j];
    const float px = pt.x, py = pt.y, pz = pt.z;
    const long long oi = (long long)__float_as_int(pt.w);

    const float scl = 0.5f * (RES - 1);
    const float fx = (px + 1.f) * scl, fy = (py + 1.f) * scl, fz = (pz + 1.f) * scl;
    const float xf = floorf(fx), yf = floorf(fy), zf = floorf(fz);
    const float wx = fx - xf, wy = fy - yf, wz = fz - zf;
    int x0 = min(max((int)xf, 0), RES - 1);
    int y0 = min(max((int)yf, 0), RES - 1);
    int z0 = min(max((int)zf, 0), RES - 1);
    const int x1 = min(x0 + 1, RES - 1);
    const int y1 = min(y0 + 1, RES - 1);
    const int z1 = min(z0 + 1, RES - 1);

    const uint4* Pxy = (const uint4*)planesH;                        // plane 0
    const uint4* Pxz = (const uint4*)(planesH + (size_t)HW * CCH);   // plane 1
    const uint4* Pyz = (const uint4*)(planesH + (size_t)2 * HW * CCH);
    const uint4* Lx = (const uint4*)linesH;
    const uint4* Ly = (const uint4*)(linesH + (size_t)RES * CCH);
    const uint4* Lz = (const uint4*)(linesH + (size_t)2 * RES * CCH);

    float2 acc[14];
    #pragma unroll
    for (int f = 0; f < 14; ++f) acc[f] = make_float2(0.f, 0.f);

    // group a: xy-plane (cols x, rows y) * z-line, basis rows 0..15
    do_half(Pxy, Lz, y0*RES+x0, y0*RES+x1, y1*RES+x0, y1*RES+x1, z0, z1, wx, wy, wz, 0,  0, bp, acc);
    do_half(Pxy, Lz, y0*RES+x0, y0*RES+x1, y1*RES+x0, y1*RES+x1, z0, z1, wx, wy, wz, 1,  0, bp, acc);
    // group b: xz-plane (cols x, rows z) * y-line, basis rows 16..31
    do_half(Pxz, Ly, z0*RES+x0, z0*RES+x1, z1*RES+x0, z1*RES+x1, y0, y1, wx, wz, wy, 0, 16, bp, acc);
    do_half(Pxz, Ly, z0*RES+x0, z0*RES+x1, z1*RES+x0, z1*RES+x1, y0, y1, wx, wz, wy, 1, 16, bp, acc);
    // group c: yz-plane (cols y, rows z) * x-line, basis rows 32..47
    do_half(Pyz, Lx, z0*RES+y0, z0*RES+y1, z1*RES+y0, z1*RES+y1, x0, x1, wy, wz, wx, 0, 32, bp, acc);
    do_half(Pyz, Lx, z0*RES+y0, z0*RES+y1, z1*RES+y0, z1*RES+y1, x0, x1, wy, wz, wx, 1, 32, bp, acc);

    float* op = out + oi * FD;
    #pragma unroll
    for (int f = 0; f < 14; ++f) {
        op[2*f] = acc[f].x;
        if (2*f + 1 < FD) op[2*f + 1] = acc[f].y;
    }
}

// ---------------- fallback (no workspace) ----------------
__device__ __forceinline__ float bilerp(const float* __restrict__ p,
                                        int o00, int o01, int o10, int o11,
                                        float wc, float wr) {
    float v00 = p[o00], v01 = p[o01], v10 = p[o10], v11 = p[o11];
    float top = v00 + wc * (v01 - v00);
    float bot = v10 + wc * (v11 - v10);
    return top + wr * (bot - top);
}

__global__ __launch_bounds__(BLK) void vm_eval_fallback(
    const float* __restrict__ pts,
    const float* __restrict__ pxy, const float* __restrict__ pyz, const float* __restrict__ pxz,
    const float* __restrict__ vx, const float* __restrict__ vy, const float* __restrict__ vz,
    const float* __restrict__ basis, float* __restrict__ out) {
    const long long i = (long long)blockIdx.x * BLK + threadIdx.x;
    const float px = pts[i*3], py = pts[i*3+1], pz = pts[i*3+2];
    const float scl = 0.5f * (RES - 1);
    const float fx = (px + 1.f) * scl, fy = (py + 1.f) * scl, fz = (pz + 1.f) * scl;
    const float xf = floorf(fx), yf = floorf(fy), zf = floorf(fz);
    const float wx = fx - xf, wy = fy - yf, wz = fz - zf;
    int x0 = min(max((int)xf, 0), RES - 1);
    int y0 = min(max((int)yf, 0), RES - 1);
    int z0 = min(max((int)zf, 0), RES - 1);
    const int x1 = min(x0+1, RES-1), y1 = min(y0+1, RES-1), z1 = min(z0+1, RES-1);
    float acc[FD];
    #pragma unroll
    for (int f = 0; f < FD; ++f) acc[f] = 0.f;
    #pragma unroll 4
    for (int c = 0; c < CCH; ++c) {
        const float* a = pxy + c * HW;
        const float* b = pxz + c * HW;
        const float* d = pyz + c * HW;
        float lz = vz[c*RES+z0]; lz += wz * (vz[c*RES+z1] - lz);
        float ly = vy[c*RES+y0]; ly += wy * (vy[c*RES+y1] - ly);
        float lx = vx[c*RES+x0]; lx += wx * (vx[c*RES+x1] - lx);
        const float fa = bilerp(a, y0*RES+x0, y0*RES+x1, y1*RES+x0, y1*RES+x1, wx, wy) * lz;
        const float fb = bilerp(b, z0*RES+x0, z0*RES+x1, z1*RES+x0, z1*RES+x1, wx, wz) * ly;
        const float fc = bilerp(d, z0*RES+y0, z0*RES+y1, z1*RES+y0, z1*RES+y1, wy, wz) * lx;
        #pragma unroll
        for (int f = 0; f < FD; ++f)
            acc[f] += fa * basis[c*FD+f] + fb * basis[(CCH+c)*FD+f] + fc * basis[(2*CCH+c)*FD+f];
    }
    float* op = out + i * FD;
    #pragma unroll
    for (int f = 0; f < FD; ++f) op[f] = acc[f];
}

extern "C" void kernel_launch(void* const* d_in, const int* in_sizes, int n_in,
                              void* d_out, int out_size, void* d_ws, size_t ws_size,
                              hipStream_t stream) {
    const float* pts   = (const float*)d_in[0];
    const float* pxy   = (const float*)d_in[1];
    const float* pyz   = (const float*)d_in[2];
    const float* pxz   = (const float*)d_in[3];
    const float* vx    = (const float*)d_in[4];
    const float* vy    = (const float*)d_in[5];
    const float* vz    = (const float*)d_in[6];
    const float* basis = (const float*)d_in[7];
    float* out = (float*)d_out;

    if (ws_size < WS_NEED) {
        vm_eval_fallback<<<NPTS / BLK, BLK, 0, stream>>>(pts, pxy, pyz, pxz, vx, vy, vz, basis, out);
        return;
    }

    uint8_t* w = (uint8_t*)d_ws;
    __half*   planesH = (__half*)(w + WS_PLANEH);
    __half*   linesH  = (__half*)(w + WS_LINEH);
    float2*   bpad    = (float2*)(w + WS_BPAD);
    unsigned* hist    = (unsigned*)(w + WS_HIST);
    unsigned* cursor  = (unsigned*)(w + WS_CURSOR);
    float4*   sorted  = (float4*)(w + WS_SORTED);

    hipMemsetAsync(hist, 0, (size_t)NCELL * 4, stream);
    transform_all<<<1205, BLK, 0, stream>>>(pxy, pxz, pyz, vx, vy, vz, basis, planesH, linesH, bpad);
    hist_kernel<<<NPTS / BLK, BLK, 0, stream>>>(pts, hist);
    scan_kernel<<<1, 1024, 0, stream>>>(hist, cursor);
    scatter_kernel<<<NPTS / BLK, BLK, 0, stream>>>(pts, cursor, sorted);
    eval_kernel<<<NPTS / BLK, BLK, 0, stream>>>(sorted, planesH, linesH, bpad, out);
}